// Round 2
// baseline (294.422 us; speedup 1.0000x reference)
//
#include <hip/hip_runtime.h>
#include <hip/hip_bf16.h>

#define T_SEQ 4096
#define DIM   256
#define NBATCH 4

typedef short s8v __attribute__((ext_vector_type(8)));   // 8 bf16 (A/B frag)
typedef float f4v __attribute__((ext_vector_type(4)));   // 4 fp32 (C/D frag)
typedef unsigned short u16;

#define MFMA16(a,b,c) __builtin_amdgcn_mfma_f32_16x16x32_bf16(a,b,c,0,0,0)
#define FENCE_LGKM() asm volatile("s_waitcnt lgkmcnt(0)" ::: "memory")

// dynamic task counters, one per batch; zeroed by wtrans_kernel each launch
__device__ int g_cnt[4];

static __device__ __forceinline__ u16 f2bf(float f) {
  union { float f; unsigned int u; } c; c.f = f;
  unsigned int u = c.u;
  unsigned int r = (u + 0x7fffu + ((u >> 16) & 1u)) >> 16;   // RNE
  return (u16)r;
}

// pack 8 consecutive fp32 -> 8 bf16 (A-frag source)
static __device__ __forceinline__ s8v pack8(const float* p) {
  float4 a = *(const float4*)p;
  float4 b = *(const float4*)(p + 4);
  s8v r;
  r[0] = (short)f2bf(a.x); r[1] = (short)f2bf(a.y);
  r[2] = (short)f2bf(a.z); r[3] = (short)f2bf(a.w);
  r[4] = (short)f2bf(b.x); r[5] = (short)f2bf(b.y);
  r[6] = (short)f2bf(b.z); r[7] = (short)f2bf(b.w);
  return r;
}

// ---------- diagnostic fallback (fp32 out) ----------
__global__ void diag_fill_kernel(float* __restrict__ out, float val, int n) {
  int i = blockIdx.x * blockDim.x + threadIdx.x;
  if (i < n) out[i] = val;
}

// ---------- kernel 1: Wt[n][k] = bf16(W[k][n]) for the 3 weight matrices ----------
__global__ void wtrans_kernel(const float* __restrict__ Wq, const float* __restrict__ Wk,
                              const float* __restrict__ Wv, u16* __restrict__ Wt) {
  if (blockIdx.x == 0 && blockIdx.y == 0 && blockIdx.z == 0 &&
      threadIdx.y == 0 && threadIdx.x < 4)
    g_cnt[threadIdx.x] = 0;                    // reset attn task queues (stream-ordered)
  __shared__ float tile[32][33];
  int m = blockIdx.z;
  const float* W = (m == 0) ? Wq : ((m == 1) ? Wk : Wv);
  int bx = blockIdx.x * 32, by = blockIdx.y * 32;
  int x = threadIdx.x, y = threadIdx.y;          // block (32,8)
  #pragma unroll
  for (int i = 0; i < 32; i += 8) tile[y + i][x] = W[(by + y + i) * DIM + bx + x];
  __syncthreads();
  u16* o = Wt + m * DIM * DIM;
  #pragma unroll
  for (int i = 0; i < 32; i += 8) o[(bx + y + i) * DIM + by + x] = f2bf(tile[x][y + i]);
}

// ---------- kernel 2: K / V^T projections -> FRAGMENT-MAJOR tile format ------
// (unchanged from previous round)
__global__ __launch_bounds__(256) void proj_kernel(
    const float* __restrict__ x, const u16* __restrict__ Wt,
    const float* __restrict__ bk, const float* __restrict__ bv,
    u16* __restrict__ kf, u16* __restrict__ vf) {
  alignas(16) __shared__ u16 Kl[64 * 264];       // K rows, pad 256->264
  alignas(16) __shared__ u16 Vl[256 * 72];       // V^T [c][t_local], pad 64->72

  int bid = blockIdx.x;
  int which = blockIdx.y;                        // 0 = K, 1 = V
  int tid  = threadIdx.x;
  int wave = tid >> 6, lane = tid & 63, quad = lane >> 4, l16 = lane & 15;
  int row0 = bid * 64 + wave * 16;

  s8v a[8];
  const float* xp = x + (size_t)(row0 + l16) * DIM + quad * 8;
  #pragma unroll
  for (int ks = 0; ks < 8; ks++) a[ks] = pack8(xp + ks * 32);

  if (which == 0) {
    const u16* W = Wt + DIM * DIM;               // Wk^T
    f4v acc[16];
    #pragma unroll
    for (int nt = 0; nt < 16; nt++) acc[nt] = (f4v){0.f, 0.f, 0.f, 0.f};
    #pragma unroll
    for (int ks = 0; ks < 8; ks++) {
      #pragma unroll
      for (int nt = 0; nt < 16; nt++) {
        s8v bfr = *(const s8v*)(W + (nt * 16 + l16) * DIM + ks * 32 + quad * 8);
        acc[nt] = MFMA16(a[ks], bfr, acc[nt]);
      }
    }
    #pragma unroll
    for (int nt = 0; nt < 16; nt++) {
      float bb = bk[nt * 16 + l16];
      #pragma unroll
      for (int r = 0; r < 4; r++)
        Kl[(wave * 16 + quad * 4 + r) * 264 + nt * 16 + l16] = f2bf(acc[nt][r] + bb);
    }
    __syncthreads();
    #pragma unroll
    for (int i = 0; i < 8; i++) {                // 2048 chunks, 8/thread
      int o = tid + i * 256;
      int tile = o >> 10, rem = o & 1023;
      int f = rem >> 6, ln = rem & 63;
      int sl = tile * 32 + (f >> 3) * 16 + (ln & 15);
      int c  = (f & 7) * 32 + (ln >> 4) * 8;
      s8v v = *(const s8v*)&Kl[sl * 264 + c];
      *(s8v*)&kf[(((size_t)(bid * 2 + tile) * 16 + f) * 64 + ln) * 8] = v;
    }
  } else {
    const u16* W = Wt + 2 * DIM * DIM;           // Wv^T
    f4v acc[16];
    #pragma unroll
    for (int nt = 0; nt < 16; nt++) acc[nt] = (f4v){0.f, 0.f, 0.f, 0.f};
    #pragma unroll
    for (int ks = 0; ks < 8; ks++) {
      #pragma unroll
      for (int nt = 0; nt < 16; nt++) {
        s8v bfr = *(const s8v*)(W + (nt * 16 + l16) * DIM + ks * 32 + quad * 8);
        acc[nt] = MFMA16(a[ks], bfr, acc[nt]);
      }
    }
    #pragma unroll
    for (int nt = 0; nt < 16; nt++) {
      float bb = bv[nt * 16 + l16];
      union { u16 h[4]; uint2 v2; } pk;
      #pragma unroll
      for (int r = 0; r < 4; r++) pk.h[r] = f2bf(acc[nt][r] + bb);
      *(uint2*)&Vl[(nt * 16 + l16) * 72 + wave * 16 + quad * 4] = pk.v2;
    }
    __syncthreads();
    #pragma unroll
    for (int i = 0; i < 8; i++) {                // 2048 chunks, 8/thread
      int o = tid + i * 256;
      int tile = o >> 10, rem = o & 1023;
      int nt = rem >> 6, ln = rem & 63;
      int c  = nt * 16 + (ln & 15);
      int sl = tile * 32 + (ln >> 4) * 8;
      s8v v = *(const s8v*)&Vl[c * 72 + sl];
      *(s8v*)&vf[(((size_t)(bid * 2 + tile) * 16 + nt) * 64 + ln) * 8] = v;
    }
  }
}

// ---------- kernel 3: flash attention, causal, dynamic 16-row tasks ----------
// grid 768 (3 blocks/CU by LDS+VGPR), block 256 (4 waves). b = bid&3 keeps
// batch<->XCD-pair L2 affinity. Per-batch atomic counter hands out 16-row
// Q-tiles in DESCENDING size order (q = 255-t) -> no static-pairing tail.
// Within a task: all 4 waves share the 16 Q rows; KV range [0,n) split 4-way.
// Register diet for 3 waves/SIMD: K frags in two 8-frag batches, V frags
// loaded after S (covered by exp + PV ordering), no cross-iter K prefetch —
// 12 resident waves/CU provide the latency hiding instead.
__global__ __launch_bounds__(256, 3) void attn_kernel(
    const float* __restrict__ x, const u16* __restrict__ wtq, const float* __restrict__ bq,
    const u16* __restrict__ kf, const u16* __restrict__ vf, float* __restrict__ out) {
  alignas(16) __shared__ u16 Qs[16 * 264];        // 8.25 KB, pad 256->264 (2-way reads)
  alignas(16) __shared__ float ObA[16 * 258];     // 16.1 KB, pad 256->258
  alignas(16) __shared__ float ObB[16 * 258];     // 16.1 KB
  alignas(16) __shared__ u16 Ps[4 * 640];         // per-wave P staging, stride 40
  __shared__ float lbuf[4][16];
  __shared__ int taskS;

  int bid = blockIdx.x;
  int b = bid & 3;
  int tid = threadIdx.x;
  int wave = tid >> 6, lane = tid & 63, quad = lane >> 4, l16 = lane & 15;

  const u16* kfb = kf + (size_t)b * 128 * 8192;
  const u16* vfb = vf + (size_t)b * 128 * 8192;

  for (;;) {
    if (tid == 0) taskS = atomicAdd(&g_cnt[b], 1);
    __syncthreads();                              // also orders prev-task LDS reads
    int t = taskS;
    if (t >= 256) break;
    int q = 255 - t;                              // 16-row tile, biggest first
    int row0 = q * 16;

    // ---- Q projection: wave computes output-col group [wave*4, wave*4+4) ----
    {
      s8v xa[8];
      const float* xp = x + (size_t)(b * T_SEQ + row0 + l16) * DIM + quad * 8;
      #pragma unroll
      for (int ks = 0; ks < 8; ks++) xa[ks] = pack8(xp + ks * 32);
      f4v qacc[4];
      #pragma unroll
      for (int j = 0; j < 4; j++) qacc[j] = (f4v){0.f, 0.f, 0.f, 0.f};
      #pragma unroll
      for (int ks = 0; ks < 8; ks++) {
        #pragma unroll
        for (int j = 0; j < 4; j++) {
          int nt = wave * 4 + j;
          s8v bfr = *(const s8v*)(wtq + (nt * 16 + l16) * DIM + ks * 32 + quad * 8);
          qacc[j] = MFMA16(xa[ks], bfr, qacc[j]);
        }
      }
      #pragma unroll
      for (int j = 0; j < 4; j++) {
        int nt = wave * 4 + j;
        float bb = bq[nt * 16 + l16];
        #pragma unroll
        for (int r = 0; r < 4; r++)
          Qs[(quad * 4 + r) * 264 + nt * 16 + l16] =
              f2bf((qacc[j][r] + bb) * 0.0625f);   // pre-scale 1/sqrt(256)
      }
    }
    __syncthreads();                              // Q staged
    s8v qa[8];
    #pragma unroll
    for (int ks = 0; ks < 8; ks++)
      qa[ks] = *(const s8v*)&Qs[l16 * 264 + ks * 32 + quad * 8];
    // no barrier needed here: Qs/Obuf are disjoint; epilogue barriers order reuse

    int n = (q >> 1) + 1;                         // causal kv-tile count
    int lo = (n * wave) >> 2, hi = (n * (wave + 1)) >> 2;

    f4v o[16];
    #pragma unroll
    for (int nt = 0; nt < 16; nt++) o[nt] = (f4v){0.f, 0.f, 0.f, 0.f};
    float lrow[4] = {0.f, 0.f, 0.f, 0.f};

    #pragma unroll 1
    for (int kv = lo; kv < hi; kv++) {
      const u16* kt = kfb + (size_t)kv * 8192;
      const u16* vt = vfb + (size_t)kv * 8192;
      s8v kfr0[8], kfr1[8];
      #pragma unroll
      for (int f = 0; f < 8; f++) kfr0[f] = *(const s8v*)(kt + (f * 64 + lane) * 8);
      #pragma unroll
      for (int f = 0; f < 8; f++) kfr1[f] = *(const s8v*)(kt + ((8 + f) * 64 + lane) * 8);

      f4v c0 = (f4v){0.f, 0.f, 0.f, 0.f}, c1 = (f4v){0.f, 0.f, 0.f, 0.f};
      #pragma unroll
      for (int ks = 0; ks < 8; ks++) c0 = MFMA16(qa[ks], kfr0[ks], c0);
      s8v vfr0[8];                                // issue V first half during S(nt1)
      #pragma unroll
      for (int f = 0; f < 8; f++) vfr0[f] = *(const s8v*)(vt + (f * 64 + lane) * 8);
      #pragma unroll
      for (int ks = 0; ks < 8; ks++) c1 = MFMA16(qa[ks], kfr1[ks], c1);
      s8v vfr1[8];                                // second half covered by exp+PV0
      #pragma unroll
      for (int f = 0; f < 8; f++) vfr1[f] = *(const s8v*)(vt + ((8 + f) * 64 + lane) * 8);

      // p = exp(s); causal mask -> exact 0
      int s0 = kv * 32 + l16;
      #pragma unroll
      for (int r = 0; r < 4; r++) {
        int tq = row0 + quad * 4 + r;
        float v0 = (s0 > tq)      ? -1e30f : c0[r];
        float v1 = (s0 + 16 > tq) ? -1e30f : c1[r];
        float p0 = __expf(v0);
        float p1 = __expf(v1);
        Ps[wave * 640 + (quad * 4 + r) * 40 + l16]      = f2bf(p0);
        Ps[wave * 640 + (quad * 4 + r) * 40 + 16 + l16] = f2bf(p1);
        lrow[r] += p0 + p1;
      }
      FENCE_LGKM();                               // Ps write->read (same wave)
      s8v pa = *(const s8v*)&Ps[wave * 640 + l16 * 40 + quad * 8];
      #pragma unroll
      for (int nt = 0; nt < 8; nt++) o[nt] = MFMA16(pa, vfr0[nt], o[nt]);
      #pragma unroll
      for (int nt = 0; nt < 8; nt++) o[8 + nt] = MFMA16(pa, vfr1[nt], o[8 + nt]);
    }

    // reduce l partials across the 16 lanes of each row
    #pragma unroll
    for (int r = 0; r < 4; r++) {
      #pragma unroll
      for (int d = 1; d < 16; d <<= 1) lrow[r] += __shfl_xor(lrow[r], d);
    }
    if (l16 == 0) {
      #pragma unroll
      for (int r = 0; r < 4; r++) lbuf[wave][quad * 4 + r] = lrow[r];
    }

    // ---- combine the 4 KV-chunk partials: w0->A, w1->B | w2+=A, w3+=B ----
    float* Obw = (wave & 1) ? ObB : ObA;
    if (wave < 2) {
      #pragma unroll
      for (int nt = 0; nt < 16; nt++) {
        #pragma unroll
        for (int r = 0; r < 4; r++)
          Obw[(quad * 4 + r) * 258 + nt * 16 + l16] = o[nt][r];
      }
    }
    __syncthreads();
    if (wave >= 2) {
      #pragma unroll
      for (int nt = 0; nt < 16; nt++) {
        #pragma unroll
        for (int r = 0; r < 4; r++)
          Obw[(quad * 4 + r) * 258 + nt * 16 + l16] += o[nt][r];
      }
    }
    __syncthreads();
    // final: row = i, col = tid (coalesced fp32 stores)
    #pragma unroll
    for (int row = 0; row < 16; row++) {
      float s = lbuf[0][row] + lbuf[1][row] + lbuf[2][row] + lbuf[3][row];
      out[((size_t)(b * T_SEQ + row0 + row)) * DIM + tid] =
          (ObA[row * 258 + tid] + ObB[row * 258 + tid]) * (1.0f / s);
    }
  }
}

extern "C" void kernel_launch(void* const* d_in, const int* in_sizes, int n_in,
                              void* d_out, int out_size, void* d_ws, size_t ws_size,
                              hipStream_t stream) {
  const float* x  = (const float*)d_in[0];
  const float* Wq = (const float*)d_in[1];
  const float* bq = (const float*)d_in[2];
  const float* Wk = (const float*)d_in[3];
  const float* bk = (const float*)d_in[4];
  const float* Wv = (const float*)d_in[5];
  const float* bv = (const float*)d_in[6];

  const size_t NTD = (size_t)NBATCH * T_SEQ * DIM;             // 4,194,304 elems
  const size_t WT_ELEMS = (size_t)3 * DIM * DIM;               //   196,608 elems
  const size_t REQ_BYTES = (WT_ELEMS + 2 * NTD) * sizeof(u16); // 17,170,432 B

  if (ws_size < REQ_BYTES) {
    float val = (float)(ws_size >> 20);   // diagnostic: absmax encodes ws MiB
    diag_fill_kernel<<<(out_size + 255) / 256, 256, 0, stream>>>((float*)d_out, val, out_size);
    return;
  }

  u16* ws = (u16*)d_ws;
  u16* WT = ws;                    // [0]=Wq^T [1]=Wk^T [2]=Wv^T, 384 KiB
  u16* Kf = ws + WT_ELEMS;         // 8 MiB, frag-major K tiles
  u16* Vf = Kf + NTD;              // 8 MiB, frag-major V^T tiles

  wtrans_kernel<<<dim3(8, 8, 3), dim3(32, 8, 1), 0, stream>>>(Wq, Wk, Wv, WT);
  proj_kernel<<<dim3(256, 2, 1), dim3(256, 1, 1), 0, stream>>>(x, WT, bk, bv, Kf, Vf);
  attn_kernel<<<dim3(768, 1, 1), dim3(256, 1, 1), 0, stream>>>(x, WT, bq, Kf, Vf, (float*)d_out);
}

// Round 3
// 220.794 us; speedup vs baseline: 1.3335x; 1.3335x over previous
//
#include <hip/hip_runtime.h>
#include <hip/hip_bf16.h>

#define T_SEQ 4096
#define DIM   256
#define NBATCH 4

typedef short s8v __attribute__((ext_vector_type(8)));   // 8 bf16 (A/B frag)
typedef float f4v __attribute__((ext_vector_type(4)));   // 4 fp32 (C/D frag)
typedef unsigned short u16;

#define MFMA16(a,b,c) __builtin_amdgcn_mfma_f32_16x16x32_bf16(a,b,c,0,0,0)
#define FENCE_LGKM() asm volatile("s_waitcnt lgkmcnt(0)" ::: "memory")

// dynamic task counters, one per batch; zeroed by wtrans_kernel each launch
__device__ int g_cnt[4];

static __device__ __forceinline__ u16 f2bf(float f) {
  union { float f; unsigned int u; } c; c.f = f;
  unsigned int u = c.u;
  unsigned int r = (u + 0x7fffu + ((u >> 16) & 1u)) >> 16;   // RNE
  return (u16)r;
}

// pack 8 consecutive fp32 -> 8 bf16 (A-frag source)
static __device__ __forceinline__ s8v pack8(const float* p) {
  float4 a = *(const float4*)p;
  float4 b = *(const float4*)(p + 4);
  s8v r;
  r[0] = (short)f2bf(a.x); r[1] = (short)f2bf(a.y);
  r[2] = (short)f2bf(a.z); r[3] = (short)f2bf(a.w);
  r[4] = (short)f2bf(b.x); r[5] = (short)f2bf(b.y);
  r[6] = (short)f2bf(b.z); r[7] = (short)f2bf(b.w);
  return r;
}

// ---------- diagnostic fallback (fp32 out) ----------
__global__ void diag_fill_kernel(float* __restrict__ out, float val, int n) {
  int i = blockIdx.x * blockDim.x + threadIdx.x;
  if (i < n) out[i] = val;
}

// ---------- kernel 1: Wt[n][k] = bf16(W[k][n]) for the 3 weight matrices ----------
__global__ void wtrans_kernel(const float* __restrict__ Wq, const float* __restrict__ Wk,
                              const float* __restrict__ Wv, u16* __restrict__ Wt) {
  if (blockIdx.x == 0 && blockIdx.y == 0 && blockIdx.z == 0 &&
      threadIdx.y == 0 && threadIdx.x < 4)
    g_cnt[threadIdx.x] = 0;                    // reset attn task queues (stream-ordered)
  __shared__ float tile[32][33];
  int m = blockIdx.z;
  const float* W = (m == 0) ? Wq : ((m == 1) ? Wk : Wv);
  int bx = blockIdx.x * 32, by = blockIdx.y * 32;
  int x = threadIdx.x, y = threadIdx.y;          // block (32,8)
  #pragma unroll
  for (int i = 0; i < 32; i += 8) tile[y + i][x] = W[(by + y + i) * DIM + bx + x];
  __syncthreads();
  u16* o = Wt + m * DIM * DIM;
  #pragma unroll
  for (int i = 0; i < 32; i += 8) o[(bx + y + i) * DIM + by + x] = f2bf(tile[x][y + i]);
}

// ---------- kernel 2: K / V^T projections -> FRAGMENT-MAJOR tile format ------
// (unchanged)
__global__ __launch_bounds__(256) void proj_kernel(
    const float* __restrict__ x, const u16* __restrict__ Wt,
    const float* __restrict__ bk, const float* __restrict__ bv,
    u16* __restrict__ kf, u16* __restrict__ vf) {
  alignas(16) __shared__ u16 Kl[64 * 264];       // K rows, pad 256->264
  alignas(16) __shared__ u16 Vl[256 * 72];       // V^T [c][t_local], pad 64->72

  int bid = blockIdx.x;
  int which = blockIdx.y;                        // 0 = K, 1 = V
  int tid  = threadIdx.x;
  int wave = tid >> 6, lane = tid & 63, quad = lane >> 4, l16 = lane & 15;
  int row0 = bid * 64 + wave * 16;

  s8v a[8];
  const float* xp = x + (size_t)(row0 + l16) * DIM + quad * 8;
  #pragma unroll
  for (int ks = 0; ks < 8; ks++) a[ks] = pack8(xp + ks * 32);

  if (which == 0) {
    const u16* W = Wt + DIM * DIM;               // Wk^T
    f4v acc[16];
    #pragma unroll
    for (int nt = 0; nt < 16; nt++) acc[nt] = (f4v){0.f, 0.f, 0.f, 0.f};
    #pragma unroll
    for (int ks = 0; ks < 8; ks++) {
      #pragma unroll
      for (int nt = 0; nt < 16; nt++) {
        s8v bfr = *(const s8v*)(W + (nt * 16 + l16) * DIM + ks * 32 + quad * 8);
        acc[nt] = MFMA16(a[ks], bfr, acc[nt]);
      }
    }
    #pragma unroll
    for (int nt = 0; nt < 16; nt++) {
      float bb = bk[nt * 16 + l16];
      #pragma unroll
      for (int r = 0; r < 4; r++)
        Kl[(wave * 16 + quad * 4 + r) * 264 + nt * 16 + l16] = f2bf(acc[nt][r] + bb);
    }
    __syncthreads();
    #pragma unroll
    for (int i = 0; i < 8; i++) {                // 2048 chunks, 8/thread
      int o = tid + i * 256;
      int tile = o >> 10, rem = o & 1023;
      int f = rem >> 6, ln = rem & 63;
      int sl = tile * 32 + (f >> 3) * 16 + (ln & 15);
      int c  = (f & 7) * 32 + (ln >> 4) * 8;
      s8v v = *(const s8v*)&Kl[sl * 264 + c];
      *(s8v*)&kf[(((size_t)(bid * 2 + tile) * 16 + f) * 64 + ln) * 8] = v;
    }
  } else {
    const u16* W = Wt + 2 * DIM * DIM;           // Wv^T
    f4v acc[16];
    #pragma unroll
    for (int nt = 0; nt < 16; nt++) acc[nt] = (f4v){0.f, 0.f, 0.f, 0.f};
    #pragma unroll
    for (int ks = 0; ks < 8; ks++) {
      #pragma unroll
      for (int nt = 0; nt < 16; nt++) {
        s8v bfr = *(const s8v*)(W + (nt * 16 + l16) * DIM + ks * 32 + quad * 8);
        acc[nt] = MFMA16(a[ks], bfr, acc[nt]);
      }
    }
    #pragma unroll
    for (int nt = 0; nt < 16; nt++) {
      float bb = bv[nt * 16 + l16];
      union { u16 h[4]; uint2 v2; } pk;
      #pragma unroll
      for (int r = 0; r < 4; r++) pk.h[r] = f2bf(acc[nt][r] + bb);
      *(uint2*)&Vl[(nt * 16 + l16) * 72 + wave * 16 + quad * 4] = pk.v2;
    }
    __syncthreads();
    #pragma unroll
    for (int i = 0; i < 8; i++) {                // 2048 chunks, 8/thread
      int o = tid + i * 256;
      int tile = o >> 10, rem = o & 1023;
      int nt = rem >> 6, ln = rem & 63;
      int c  = nt * 16 + (ln & 15);
      int sl = tile * 32 + (ln >> 4) * 8;
      s8v v = *(const s8v*)&Vl[c * 72 + sl];
      *(s8v*)&vf[(((size_t)(bid * 2 + tile) * 16 + nt) * 64 + ln) * 8] = v;
    }
  }
}

// ---------- kernel 3: flash attention, causal, dynamic 16-row tasks ----------
// grid 512, block 256 (4 waves), __launch_bounds__(256,2) -> NO SPILLS (r1's
// (256,3) capped regs at ~170 and spilled: FETCH 27->349MB, WRITE 20->90MB,
// VGPR 84 = allocator jammed at the cap. (256,2) compiles this body to
// 128 VGPR + 64 AGPR, zero scratch — measured in round 0).
// Per-batch atomic counter hands out 16-row Q-tiles in DESCENDING size order
// (no static-pairing tail); 4 waves split the KV range 4-way, combine in LDS.
__global__ __launch_bounds__(256, 2) void attn_kernel(
    const float* __restrict__ x, const u16* __restrict__ wtq, const float* __restrict__ bq,
    const u16* __restrict__ kf, const u16* __restrict__ vf, float* __restrict__ out) {
  alignas(16) __shared__ u16 Qs[16 * 264];        // 8.25 KB, pad 256->264 (2-way reads)
  alignas(16) __shared__ float ObA[16 * 258];     // 16.1 KB, pad 256->258
  alignas(16) __shared__ float ObB[16 * 258];     // 16.1 KB
  alignas(16) __shared__ u16 Ps[4 * 640];         // per-wave P staging, stride 40
  __shared__ float lbuf[4][16];
  __shared__ int taskS;

  int bid = blockIdx.x;
  int b = bid & 3;
  int tid = threadIdx.x;
  int wave = tid >> 6, lane = tid & 63, quad = lane >> 4, l16 = lane & 15;

  const u16* kfb = kf + (size_t)b * 128 * 8192;
  const u16* vfb = vf + (size_t)b * 128 * 8192;

  for (;;) {
    if (tid == 0) taskS = atomicAdd(&g_cnt[b], 1);
    __syncthreads();                              // also orders prev-task LDS reads
    int t = taskS;
    if (t >= 256) break;
    int q = 255 - t;                              // 16-row tile, biggest first
    int row0 = q * 16;

    // ---- Q projection: wave computes output-col group [wave*4, wave*4+4) ----
    {
      s8v xa[8];
      const float* xp = x + (size_t)(b * T_SEQ + row0 + l16) * DIM + quad * 8;
      #pragma unroll
      for (int ks = 0; ks < 8; ks++) xa[ks] = pack8(xp + ks * 32);
      f4v qacc[4];
      #pragma unroll
      for (int j = 0; j < 4; j++) qacc[j] = (f4v){0.f, 0.f, 0.f, 0.f};
      #pragma unroll
      for (int ks = 0; ks < 8; ks++) {
        #pragma unroll
        for (int j = 0; j < 4; j++) {
          int nt = wave * 4 + j;
          s8v bfr = *(const s8v*)(wtq + (nt * 16 + l16) * DIM + ks * 32 + quad * 8);
          qacc[j] = MFMA16(xa[ks], bfr, qacc[j]);
        }
      }
      #pragma unroll
      for (int j = 0; j < 4; j++) {
        int nt = wave * 4 + j;
        float bb = bq[nt * 16 + l16];
        #pragma unroll
        for (int r = 0; r < 4; r++)
          Qs[(quad * 4 + r) * 264 + nt * 16 + l16] =
              f2bf((qacc[j][r] + bb) * 0.0625f);   // pre-scale 1/sqrt(256)
      }
    }
    __syncthreads();                              // Q staged
    s8v qa[8];
    #pragma unroll
    for (int ks = 0; ks < 8; ks++)
      qa[ks] = *(const s8v*)&Qs[l16 * 264 + ks * 32 + quad * 8];
    // no barrier needed here: Qs/Obuf are disjoint; epilogue barriers order reuse

    int n = (q >> 1) + 1;                         // causal kv-tile count
    int lo = (n * wave) >> 2, hi = (n * (wave + 1)) >> 2;

    f4v o[16];
    #pragma unroll
    for (int nt = 0; nt < 16; nt++) o[nt] = (f4v){0.f, 0.f, 0.f, 0.f};
    float lrow[4] = {0.f, 0.f, 0.f, 0.f};

    #pragma unroll 1
    for (int kv = lo; kv < hi; kv++) {
      const u16* kt = kfb + (size_t)kv * 8192;
      const u16* vt = vfb + (size_t)kv * 8192;
      s8v kfr0[8], kfr1[8];
      #pragma unroll
      for (int f = 0; f < 8; f++) kfr0[f] = *(const s8v*)(kt + (f * 64 + lane) * 8);
      #pragma unroll
      for (int f = 0; f < 8; f++) kfr1[f] = *(const s8v*)(kt + ((8 + f) * 64 + lane) * 8);

      f4v c0 = (f4v){0.f, 0.f, 0.f, 0.f}, c1 = (f4v){0.f, 0.f, 0.f, 0.f};
      #pragma unroll
      for (int ks = 0; ks < 8; ks++) c0 = MFMA16(qa[ks], kfr0[ks], c0);
      s8v vfr0[8];                                // issue V first half during S(nt1)
      #pragma unroll
      for (int f = 0; f < 8; f++) vfr0[f] = *(const s8v*)(vt + (f * 64 + lane) * 8);
      #pragma unroll
      for (int ks = 0; ks < 8; ks++) c1 = MFMA16(qa[ks], kfr1[ks], c1);
      s8v vfr1[8];                                // second half covered by exp+PV0
      #pragma unroll
      for (int f = 0; f < 8; f++) vfr1[f] = *(const s8v*)(vt + ((8 + f) * 64 + lane) * 8);

      // p = exp(s); causal mask -> exact 0
      int s0 = kv * 32 + l16;
      #pragma unroll
      for (int r = 0; r < 4; r++) {
        int tq = row0 + quad * 4 + r;
        float v0 = (s0 > tq)      ? -1e30f : c0[r];
        float v1 = (s0 + 16 > tq) ? -1e30f : c1[r];
        float p0 = __expf(v0);
        float p1 = __expf(v1);
        Ps[wave * 640 + (quad * 4 + r) * 40 + l16]      = f2bf(p0);
        Ps[wave * 640 + (quad * 4 + r) * 40 + 16 + l16] = f2bf(p1);
        lrow[r] += p0 + p1;
      }
      FENCE_LGKM();                               // Ps write->read (same wave)
      s8v pa = *(const s8v*)&Ps[wave * 640 + l16 * 40 + quad * 8];
      #pragma unroll
      for (int nt = 0; nt < 8; nt++) o[nt] = MFMA16(pa, vfr0[nt], o[nt]);
      #pragma unroll
      for (int nt = 0; nt < 8; nt++) o[8 + nt] = MFMA16(pa, vfr1[nt], o[8 + nt]);
    }

    // reduce l partials across the 16 lanes of each row
    #pragma unroll
    for (int r = 0; r < 4; r++) {
      #pragma unroll
      for (int d = 1; d < 16; d <<= 1) lrow[r] += __shfl_xor(lrow[r], d);
    }
    if (l16 == 0) {
      #pragma unroll
      for (int r = 0; r < 4; r++) lbuf[wave][quad * 4 + r] = lrow[r];
    }

    // ---- combine the 4 KV-chunk partials: w0->A, w1->B | w2+=A, w3+=B ----
    float* Obw = (wave & 1) ? ObB : ObA;
    if (wave < 2) {
      #pragma unroll
      for (int nt = 0; nt < 16; nt++) {
        #pragma unroll
        for (int r = 0; r < 4; r++)
          Obw[(quad * 4 + r) * 258 + nt * 16 + l16] = o[nt][r];
      }
    }
    __syncthreads();
    if (wave >= 2) {
      #pragma unroll
      for (int nt = 0; nt < 16; nt++) {
        #pragma unroll
        for (int r = 0; r < 4; r++)
          Obw[(quad * 4 + r) * 258 + nt * 16 + l16] += o[nt][r];
      }
    }
    __syncthreads();
    // final: row = i, col = tid (coalesced fp32 stores)
    #pragma unroll
    for (int row = 0; row < 16; row++) {
      float s = lbuf[0][row] + lbuf[1][row] + lbuf[2][row] + lbuf[3][row];
      out[((size_t)(b * T_SEQ + row0 + row)) * DIM + tid] =
          (ObA[row * 258 + tid] + ObB[row * 258 + tid]) * (1.0f / s);
    }
  }
}

extern "C" void kernel_launch(void* const* d_in, const int* in_sizes, int n_in,
                              void* d_out, int out_size, void* d_ws, size_t ws_size,
                              hipStream_t stream) {
  const float* x  = (const float*)d_in[0];
  const float* Wq = (const float*)d_in[1];
  const float* bq = (const float*)d_in[2];
  const float* Wk = (const float*)d_in[3];
  const float* bk = (const float*)d_in[4];
  const float* Wv = (const float*)d_in[5];
  const float* bv = (const float*)d_in[6];

  const size_t NTD = (size_t)NBATCH * T_SEQ * DIM;             // 4,194,304 elems
  const size_t WT_ELEMS = (size_t)3 * DIM * DIM;               //   196,608 elems
  const size_t REQ_BYTES = (WT_ELEMS + 2 * NTD) * sizeof(u16); // 17,170,432 B

  if (ws_size < REQ_BYTES) {
    float val = (float)(ws_size >> 20);   // diagnostic: absmax encodes ws MiB
    diag_fill_kernel<<<(out_size + 255) / 256, 256, 0, stream>>>((float*)d_out, val, out_size);
    return;
  }

  u16* ws = (u16*)d_ws;
  u16* WT = ws;                    // [0]=Wq^T [1]=Wk^T [2]=Wv^T, 384 KiB
  u16* Kf = ws + WT_ELEMS;         // 8 MiB, frag-major K tiles
  u16* Vf = Kf + NTD;              // 8 MiB, frag-major V^T tiles

  wtrans_kernel<<<dim3(8, 8, 3), dim3(32, 8, 1), 0, stream>>>(Wq, Wk, Wv, WT);
  proj_kernel<<<dim3(256, 2, 1), dim3(256, 1, 1), 0, stream>>>(x, WT, bk, bv, Kf, Vf);
  attn_kernel<<<dim3(512, 1, 1), dim3(256, 1, 1), 0, stream>>>(x, WT, bq, Kf, Vf, (float*)d_out);
}